// Round 5
// baseline (141.957 us; speedup 1.0000x reference)
//
#include <hip/hip_runtime.h>

#define LAMBDA_NOOBJ 0.5f
#define LAMBDA_COORD 5.0f

// Single-shot deep-MLP kernel. Each thread processes exactly one tile of 8
// cells (40 floats = ten float4 per stream). All 20 float4 loads are issued
// back-to-back and pinned above a sched_barrier(0) so the compiler cannot
// sink them into the consume phase (round-3's attempt collapsed to VGPR=36;
// VGPR_Count >= ~100 here is the verification that the interleave held).
__global__ __launch_bounds__(256, 2) void yolo_loss_kernel(
    const float4* __restrict__ pred4,
    const float4* __restrict__ targ4,
    const float* __restrict__ pred,
    const float* __restrict__ targ,
    float* __restrict__ out,   // out[1]=box, out[2]=obj, out[3]=noobj
    int npairs, int ncells) {
  const int tid = blockIdx.x * blockDim.x + threadIdx.x;

  float box = 0.f, obj = 0.f, noobj = 0.f;

  if (tid < npairs) {
    const float4* pp = pred4 + (size_t)tid * 10;
    const float4* tt = targ4 + (size_t)tid * 10;
    float4 P[10], T[10];
    // Issue all 20 independent loads before any consumption.
#pragma unroll
    for (int q = 0; q < 10; ++q) P[q] = pp[q];
#pragma unroll
    for (int q = 0; q < 10; ++q) T[q] = tt[q];
    __builtin_amdgcn_sched_barrier(0);

    float p[40], t[40];
#pragma unroll
    for (int q = 0; q < 10; ++q) {
      p[4 * q + 0] = P[q].x; p[4 * q + 1] = P[q].y;
      p[4 * q + 2] = P[q].z; p[4 * q + 3] = P[q].w;
      t[4 * q + 0] = T[q].x; t[4 * q + 1] = T[q].y;
      t[4 * q + 2] = T[q].z; t[4 * q + 3] = T[q].w;
    }
#pragma unroll
    for (int c = 0; c < 8; ++c) {
      float c_t = t[c * 5];
      float cd = c_t - p[c * 5];
      cd *= cd;
      float bd = 0.f;
#pragma unroll
      for (int k = 1; k < 5; ++k) {
        float d = t[c * 5 + k] - p[c * 5 + k];
        bd += d * d;
      }
      bool is_obj = (c_t == 1.0f);
      box   += is_obj ? bd : 0.f;
      obj   += is_obj ? cd : 0.f;
      noobj += is_obj ? 0.f : cd;
    }
  }

  // Generic tail: cells not covered by full 8-cell tiles (none for this size).
  {
    const int stride = gridDim.x * blockDim.x;
    for (int c = npairs * 8 + tid; c < ncells; c += stride) {
      const float* pc = pred + (size_t)c * 5;
      const float* tc = targ + (size_t)c * 5;
      float c_t = tc[0];
      float cd = c_t - pc[0];
      cd *= cd;
      float bd = 0.f;
#pragma unroll
      for (int k = 1; k < 5; ++k) {
        float d = tc[k] - pc[k];
        bd += d * d;
      }
      bool is_obj = (c_t == 1.0f);
      box   += is_obj ? bd : 0.f;
      obj   += is_obj ? cd : 0.f;
      noobj += is_obj ? 0.f : cd;
    }
  }

  // Wave (64-lane) reduction.
#pragma unroll
  for (int off = 32; off > 0; off >>= 1) {
    box   += __shfl_down(box, off);
    obj   += __shfl_down(obj, off);
    noobj += __shfl_down(noobj, off);
  }

  __shared__ float s[3][4];
  const int lane = threadIdx.x & 63;
  const int wid = threadIdx.x >> 6;
  if (lane == 0) {
    s[0][wid] = box;
    s[1][wid] = obj;
    s[2][wid] = noobj;
  }
  __syncthreads();
  if (threadIdx.x == 0) {
    float b = s[0][0] + s[0][1] + s[0][2] + s[0][3];
    float o = s[1][0] + s[1][1] + s[1][2] + s[1][3];
    float n = s[2][0] + s[2][1] + s[2][2] + s[2][3];
    atomicAdd(&out[1], LAMBDA_COORD * b);
    atomicAdd(&out[2], o);
    atomicAdd(&out[3], LAMBDA_NOOBJ * n);
  }
}

__global__ void yolo_loss_finalize(float* __restrict__ out) {
  out[0] = out[1] + out[2] + out[3];
}

extern "C" void kernel_launch(void* const* d_in, const int* in_sizes, int n_in,
                              void* d_out, int out_size, void* d_ws, size_t ws_size,
                              hipStream_t stream) {
  const float* pred = (const float*)d_in[0];
  const float* targ = (const float*)d_in[1];
  float* out = (float*)d_out;

  const int ncells = in_sizes[0] / 5;    // 6,553,600
  const int npairs = ncells / 8;         // 819,200 tiles of 8 cells

  // d_out is poisoned once and never re-zeroed between replays; the kernel
  // accumulates with atomics, so zero it ourselves every call.
  hipMemsetAsync(d_out, 0, out_size * sizeof(float), stream);

  const int block = 256;
  const int grid = (npairs + block - 1) / block;  // 3200 blocks, 1 tile/thread
  yolo_loss_kernel<<<grid, block, 0, stream>>>(
      (const float4*)pred, (const float4*)targ, pred, targ, out, npairs, ncells);
  yolo_loss_finalize<<<1, 1, 0, stream>>>(out);
}

// Round 7
// 99.394 us; speedup vs baseline: 1.4282x; 1.4282x over previous
//
#include <hip/hip_runtime.h>

#define LAMBDA_NOOBJ 0.5f
#define LAMBDA_COORD 5.0f

typedef float floatx4 __attribute__((ext_vector_type(4)));

// R2's coalesced-stream kernel with ONE change: nontemporal loads (nt flag)
// to bypass L3 allocation. Discriminates "L3 insertion churn caps fills at
// ~3 TB/s" vs "fabric read path caps at ~3.1 TB/s per direction".
__global__ __launch_bounds__(256) void yolo_loss_kernel(
    const floatx4* __restrict__ pred4,
    const floatx4* __restrict__ targ4,
    const float* __restrict__ pred,
    const float* __restrict__ targ,
    float* __restrict__ out,   // out[1]=box, out[2]=obj, out[3]=noobj
    long long nchunks,         // number of 256-element chunks
    long long nelem,           // total elements per input
    int nwaves) {
  const int lane = threadIdx.x & 63;
  const long long g = (long long)((blockIdx.x * blockDim.x + threadIdx.x) >> 6);

  // Element e = chunk*256 + 4*lane + c; chunk ≡ g (mod 5) since stride
  // nwaves ≡ 0 (mod 5) and 256 ≡ 1 (mod 5).
  const int r = (int)((g + 4LL * lane) % 5);   // phase of this lane's first elem
  const int cstar = (5 - r) % 5;    // component index holding conf (4 => none)
  const int r_nxt = (r + 4) % 5;    // next lane's phase
  const int prov_idx = (4 - r_nxt) & 3;  // which of my t[] the next lane needs

  float box = 0.f, obj = 0.f, noobj = 0.f;

#pragma unroll 2
  for (long long chunk = g; chunk < nchunks; chunk += nwaves) {
    const long long b4 = chunk * 64 + lane;  // float4 index
    floatx4 pq = __builtin_nontemporal_load(pred4 + b4);
    floatx4 tq = __builtin_nontemporal_load(targ4 + b4);
    float p[4] = {pq.x, pq.y, pq.z, pq.w};
    float t[4] = {tq.x, tq.y, tq.z, tq.w};

    // Conf of the cell that started in the previous lane ("cell A").
    float prov = (prov_idx == 0) ? t[0] : (prov_idx == 1) ? t[1]
               : (prov_idx == 2) ? t[2] : t[3];
    float t0a = __shfl_up(prov, 1);
    if (lane == 0 && r != 0) {
      t0a = targ[chunk * 256 - r];   // previous chunk's boundary conf
    }
    // Conf of the cell starting within this lane ("cell B"), if any.
    float tcs = (cstar == 0) ? t[0] : (cstar == 1) ? t[1]
              : (cstar == 2) ? t[2] : t[3];  // cstar==4 -> unused

#pragma unroll
    for (int c = 0; c < 4; ++c) {
      float d = t[c] - p[c];
      float d2 = d * d;
      if (c == cstar) {                 // conf element
        bool m = (t[c] == 1.0f);
        obj   += m ? d2 : 0.f;
        noobj += m ? 0.f : d2;
      } else {                          // coord element
        float t0 = (c < cstar) ? t0a : tcs;
        box += (t0 == 1.0f) ? d2 : 0.f;
      }
    }
  }

  // Generic tail (elements beyond full 256-chunks) — not hit for this size.
  {
    const long long tid = (long long)blockIdx.x * blockDim.x + threadIdx.x;
    const long long stride = (long long)gridDim.x * blockDim.x;
    for (long long e = nchunks * 256 + tid; e < nelem; e += stride) {
      long long comp = e % 5;
      float d = targ[e] - pred[e];
      float d2 = d * d;
      if (comp == 0) {
        bool m = (targ[e] == 1.0f);
        obj   += m ? d2 : 0.f;
        noobj += m ? 0.f : d2;
      } else {
        box += (targ[e - comp] == 1.0f) ? d2 : 0.f;
      }
    }
  }

  // Wave (64-lane) reduction.
#pragma unroll
  for (int off = 32; off > 0; off >>= 1) {
    box   += __shfl_down(box, off);
    obj   += __shfl_down(obj, off);
    noobj += __shfl_down(noobj, off);
  }

  __shared__ float s[3][4];
  const int wid = threadIdx.x >> 6;
  if (lane == 0) {
    s[0][wid] = box;
    s[1][wid] = obj;
    s[2][wid] = noobj;
  }
  __syncthreads();
  if (threadIdx.x == 0) {
    float b = s[0][0] + s[0][1] + s[0][2] + s[0][3];
    float o = s[1][0] + s[1][1] + s[1][2] + s[1][3];
    float n = s[2][0] + s[2][1] + s[2][2] + s[2][3];
    atomicAdd(&out[1], LAMBDA_COORD * b);
    atomicAdd(&out[2], o);
    atomicAdd(&out[3], LAMBDA_NOOBJ * n);
  }
}

__global__ void yolo_loss_finalize(float* __restrict__ out) {
  out[0] = out[1] + out[2] + out[3];
}

extern "C" void kernel_launch(void* const* d_in, const int* in_sizes, int n_in,
                              void* d_out, int out_size, void* d_ws, size_t ws_size,
                              hipStream_t stream) {
  const float* pred = (const float*)d_in[0];
  const float* targ = (const float*)d_in[1];
  float* out = (float*)d_out;

  const long long nelem = (long long)in_sizes[0];   // 32,768,000
  const long long nchunks = nelem / 256;            // 128,000

  // d_out is poisoned once and never re-zeroed between replays; the kernel
  // accumulates with atomics, so zero it ourselves every call.
  (void)hipMemsetAsync(d_out, 0, out_size * sizeof(float), stream);

  // 1280 blocks = 5120 waves: divisible by 5 (phase invariance), 5 blocks/CU,
  // and 128,000 / 5120 = 25 exact iterations per wave.
  const int block = 256;
  const int grid = 1280;
  const int nwaves = (grid * block) / 64;
  yolo_loss_kernel<<<grid, block, 0, stream>>>(
      (const floatx4*)pred, (const floatx4*)targ, pred, targ, out,
      nchunks, nelem, nwaves);
  yolo_loss_finalize<<<1, 1, 0, stream>>>(out);
}

// Round 8
// 59.902 us; speedup vs baseline: 2.3698x; 1.6593x over previous
//
#include <hip/hip_runtime.h>

#define LAMBDA_NOOBJ 0.5f
#define LAMBDA_COORD 5.0f

// R1's global_load_lds staging, upgraded to a double-buffered free-running
// pipeline with COUNTED vmcnt (never drained to 0 in the main loop).
// MLP depth lives in the DMA queue, not in VGPRs, so the compiler cannot
// re-serialize it (the failure mode of rounds 3-5). No __syncthreads in the
// loop: each wave owns its 2x10KB LDS slice and free-runs.
__global__ __launch_bounds__(256) void yolo_loss_kernel(
    const float4* __restrict__ pred4,
    const float4* __restrict__ targ4,
    const float* __restrict__ pred,
    const float* __restrict__ targ,
    float* __restrict__ out,   // out[1]=box, out[2]=obj, out[3]=noobj
    int ntiles, int ncells, int nwaves) {
  // 4 waves x 2 buffers x 640 float4 (pred 320 + targ 320) = 80 KB/block.
  __shared__ float4 smem[8][640];

  const int lane = threadIdx.x & 63;
  const int wid  = threadIdx.x >> 6;
  const int wave_gid = (blockIdx.x * blockDim.x + threadIdx.x) >> 6;

  float4* const b0 = smem[wid * 2 + 0];
  float4* const b1 = smem[wid * 2 + 1];

  float box = 0.f, obj = 0.f, noobj = 0.f;

  // Issue one tile's 10 DMA loads (5 pred + 5 targ, 1KB each) into buf.
  auto issue = [&](int tile, float4* buf) {
    const float4* pg = pred4 + (size_t)tile * 320;
    const float4* tg = targ4 + (size_t)tile * 320;
#pragma unroll
    for (int r = 0; r < 5; ++r) {
      __builtin_amdgcn_global_load_lds(
          (const __attribute__((address_space(1))) void*)(pg + r * 64 + lane),
          (__attribute__((address_space(3))) void*)(buf + r * 64), 16, 0, 0);
      __builtin_amdgcn_global_load_lds(
          (const __attribute__((address_space(1))) void*)(tg + r * 64 + lane),
          (__attribute__((address_space(3))) void*)(buf + 320 + r * 64), 16, 0, 0);
    }
  };

  // Prologue: two tiles in flight.
  if (wave_gid < ntiles) issue(wave_gid, b0);
  if (wave_gid + nwaves < ntiles) issue(wave_gid + nwaves, b1);

  int cur = 0;
  for (int t = wave_gid; t < ntiles; t += nwaves) {
    // Wait for the CURRENT tile only; keep the prefetched tile's 10 loads
    // in flight across the compute phase (counted vmcnt, T4).
    if (t + nwaves < ntiles) {
      asm volatile("s_waitcnt vmcnt(10)" ::: "memory");
    } else {
      asm volatile("s_waitcnt vmcnt(0)" ::: "memory");
    }
    __builtin_amdgcn_sched_barrier(0);

    float4* wb = cur ? b1 : b0;
    float p[20], tv[20];
#pragma unroll
    for (int j = 0; j < 5; ++j) {
      float4 a = wb[lane * 5 + j];
      float4 b = wb[320 + lane * 5 + j];
      p[j * 4 + 0] = a.x; p[j * 4 + 1] = a.y; p[j * 4 + 2] = a.z; p[j * 4 + 3] = a.w;
      tv[j * 4 + 0] = b.x; tv[j * 4 + 1] = b.y; tv[j * 4 + 2] = b.z; tv[j * 4 + 3] = b.w;
    }
    // All ds_reads retired -> data is in VGPRs; safe to overwrite this buffer.
    asm volatile("s_waitcnt lgkmcnt(0)" ::: "memory");
    __builtin_amdgcn_sched_barrier(0);

    const int tn = t + 2 * nwaves;
    if (tn < ntiles) issue(tn, wb);   // refill the just-consumed buffer

#pragma unroll
    for (int c = 0; c < 4; ++c) {
      float c_t = tv[c * 5];
      float cd = c_t - p[c * 5];
      cd *= cd;
      float bd = 0.f;
#pragma unroll
      for (int k = 1; k < 5; ++k) {
        float d = tv[c * 5 + k] - p[c * 5 + k];
        bd += d * d;
      }
      bool is_obj = (c_t == 1.0f);
      box   += is_obj ? bd : 0.f;
      obj   += is_obj ? cd : 0.f;
      noobj += is_obj ? 0.f : cd;
    }
    cur ^= 1;
  }

  // Generic scalar tail (ncells % 256 != 0) — empty for this size.
  {
    const int tid = blockIdx.x * blockDim.x + threadIdx.x;
    const int stride = gridDim.x * blockDim.x;
    for (int c = ntiles * 256 + tid; c < ncells; c += stride) {
      const float* pc = pred + (size_t)c * 5;
      const float* tc = targ + (size_t)c * 5;
      float c_t = tc[0];
      float cd = c_t - pc[0];
      cd *= cd;
      float bd = 0.f;
#pragma unroll
      for (int k = 1; k < 5; ++k) {
        float d = tc[k] - pc[k];
        bd += d * d;
      }
      bool is_obj = (c_t == 1.0f);
      box   += is_obj ? bd : 0.f;
      obj   += is_obj ? cd : 0.f;
      noobj += is_obj ? 0.f : cd;
    }
  }

  // Wave (64-lane) reduction.
#pragma unroll
  for (int off = 32; off > 0; off >>= 1) {
    box   += __shfl_down(box, off);
    obj   += __shfl_down(obj, off);
    noobj += __shfl_down(noobj, off);
  }

  __shared__ float s[3][4];
  if (lane == 0) {
    s[0][wid] = box;
    s[1][wid] = obj;
    s[2][wid] = noobj;
  }
  __syncthreads();
  if (threadIdx.x == 0) {
    float b = s[0][0] + s[0][1] + s[0][2] + s[0][3];
    float o = s[1][0] + s[1][1] + s[1][2] + s[1][3];
    float n = s[2][0] + s[2][1] + s[2][2] + s[2][3];
    atomicAdd(&out[1], LAMBDA_COORD * b);
    atomicAdd(&out[2], o);
    atomicAdd(&out[3], LAMBDA_NOOBJ * n);
  }
}

__global__ void yolo_loss_finalize(float* __restrict__ out) {
  out[0] = out[1] + out[2] + out[3];
}

extern "C" void kernel_launch(void* const* d_in, const int* in_sizes, int n_in,
                              void* d_out, int out_size, void* d_ws, size_t ws_size,
                              hipStream_t stream) {
  const float* pred = (const float*)d_in[0];
  const float* targ = (const float*)d_in[1];
  float* out = (float*)d_out;

  const int ncells = in_sizes[0] / 5;    // 6,553,600
  const int ntiles = ncells / 256;       // 25,600

  // d_out is poisoned once and never re-zeroed between replays; the kernel
  // accumulates with atomics, so zero it ourselves every call.
  (void)hipMemsetAsync(d_out, 0, out_size * sizeof(float), stream);

  // 512 blocks = exactly 2 blocks/CU (80 KB LDS each) = 2048 free-running
  // waves, ~12.5 tiles per wave.
  const int block = 256;
  const int grid = 512;
  const int nwaves = (grid * block) / 64;
  yolo_loss_kernel<<<grid, block, 0, stream>>>(
      (const float4*)pred, (const float4*)targ, pred, targ, out,
      ntiles, ncells, nwaves);
  yolo_loss_finalize<<<1, 1, 0, stream>>>(out);
}